// Round 7
// baseline (31515.738 us; speedup 1.0000x reference)
//
#include <hip/hip_runtime.h>
#include <stdint.h>
#include <math.h>

// ---------------------------------------------------------------------------
// Round 7: split-bf16 MFMA LSTM, restructured for 2 waves/SIMD.
//  * mc: 512-thr/8-wave blocks; wave (cg,rt) = 4 gate tiles of one 32-row
//    tile (acc 64 AGPR, arch ~110 regs; (512,2) caps 256 -> no spill).
//  * LDS h-frag layout swizzled: per-(kb,hs) stride 264 shorts -> epilogue
//    b16 writes conflict-free (was 16-way, 4.29e8 conflict cycles).
//  * mu/ls matmul + RNG computed redundantly by ALL waves (Bmu preloaded to
//    regs, fully unrolled) -> no serial wave-0 section.
//  * hist: 256 blocks x 256 thr (RT=1), (256,1).
// ---------------------------------------------------------------------------

#define HH     128
#define NG     512
#define NB     8192
#define NSAMP  100
#define NSTEP  20
#define TCAP   18
#define NHIST  126
#define NRET   127

using bfrag = __attribute__((ext_vector_type(8))) short;   // 8 bf16 = 4 VGPRs
using facc  = __attribute__((ext_vector_type(16))) float;  // 16 f32 acc

// LDS frag strides (shorts): per-(kb,hs) region 264 (8 pad), per-kb 528.
#define SHS 264
#define SKB 528
#define HFN 4224   // 8 kb * 528

// ----------------------------- threefry2x32 --------------------------------
__device__ __forceinline__ void tf2x32(uint32_t k0, uint32_t k1,
                                       uint32_t x0, uint32_t x1,
                                       uint32_t &y0, uint32_t &y1) {
  uint32_t ks2 = k0 ^ k1 ^ 0x1BD11BDAu;
  x0 += k0; x1 += k1;
#define RR(r) { x0 += x1; x1 = (x1 << (r)) | (x1 >> (32 - (r))); x1 ^= x0; }
  RR(13) RR(15) RR(26) RR(6)   x0 += k1;  x1 += ks2 + 1u;
  RR(17) RR(29) RR(16) RR(24)  x0 += ks2; x1 += k0  + 2u;
  RR(13) RR(15) RR(26) RR(6)   x0 += k0;  x1 += k1  + 3u;
  RR(17) RR(29) RR(16) RR(24)  x0 += k1;  x1 += ks2 + 4u;
  RR(13) RR(15) RR(26) RR(6)   x0 += ks2; x1 += k0  + 5u;
#undef RR
  y0 = x0; y1 = x1;
}

__device__ __forceinline__ float erfinv32(float x) {
  // w = -log1p(-x*x); 1-x*x is exact (Sterbenz) where it matters, so
  // __logf(1-x*x) tracks the reference log1pf path to ~1e-7.
  float w = -__logf(fmaxf(1.0f - x * x, 1e-37f));
  float p;
  if (w < 5.0f) {
    w = w - 2.5f;
    p = 2.81022636e-08f;
    p = fmaf(p, w, 3.43273939e-07f);
    p = fmaf(p, w, -3.5233877e-06f);
    p = fmaf(p, w, -4.39150654e-06f);
    p = fmaf(p, w, 0.00021858087f);
    p = fmaf(p, w, -0.00125372503f);
    p = fmaf(p, w, -0.00417768164f);
    p = fmaf(p, w, 0.246640727f);
    p = fmaf(p, w, 1.50140941f);
  } else {
    w = sqrtf(w) - 3.0f;
    p = -0.000200214257f;
    p = fmaf(p, w, 0.000100950558f);
    p = fmaf(p, w, 0.00134934322f);
    p = fmaf(p, w, -0.00367342844f);
    p = fmaf(p, w, 0.00573950773f);
    p = fmaf(p, w, -0.0076224613f);
    p = fmaf(p, w, 0.00943887047f);
    p = fmaf(p, w, 1.00167406f);
    p = fmaf(p, w, 2.83297682f);
  }
  return p * x;
}

__device__ __forceinline__ float normal32(uint32_t k0, uint32_t k1, uint32_t idx) {
  uint32_t y0, y1;
  tf2x32(k0, k1, 0u, idx, y0, y1);
  uint32_t bits = y0 ^ y1;
  float f = __uint_as_float((bits >> 9) | 0x3f800000u) - 1.0f;
  const float lo = __uint_as_float(0xBF7FFFFFu);
  float u = fmaxf(lo, f * 2.0f + lo);
  return 1.41421356f * erfinv32(u);
}

__device__ __forceinline__ float fast_sigmoid(float x) {
  return __builtin_amdgcn_rcpf(1.0f + __expf(-x));
}
__device__ __forceinline__ float fast_tanh(float x) {
  return 1.0f - 2.0f * __builtin_amdgcn_rcpf(1.0f + __expf(2.0f * x));
}

__device__ __forceinline__ unsigned short f2bf(float x) {
  uint32_t u = __float_as_uint(x);
  uint32_t r = u + 0x7fffu + ((u >> 16) & 1u);
  return (unsigned short)(r >> 16);
}
__device__ __forceinline__ float bf2f(unsigned short h) {
  return __uint_as_float(((uint32_t)h) << 16);
}

// ------------------------------- small kernels -----------------------------
__global__ void returns_kernel(const float* __restrict__ inp,
                               const float* __restrict__ pert,
                               float* __restrict__ ret) {
  int i = blockIdx.x * blockDim.x + threadIdx.x;
  if (i >= NRET * NB) return;
  int s = i / NB, b = i - s * NB;
  float p0 = inp[s * NB + b] * (1.0f + pert[s * NB + b]);
  float p1 = inp[(s + 1) * NB + b] * (1.0f + pert[(s + 1) * NB + b]);
  ret[i] = p1 - p0;
}

__global__ void keys_kernel(uint32_t* __restrict__ keys) {
  int id = blockIdx.x * blockDim.x + threadIdx.x;
  if (id >= NSAMP * NSTEP) return;
  int s = id / NSTEP, t = id - s * NSTEP;
  uint32_t sk0, sk1, k0, k1;
  tf2x32(0u, 42u, 0u, (uint32_t)s, sk0, sk1);
  tf2x32(sk0, sk1, 0u, (uint32_t)t, k0, k1);
  keys[2 * id] = k0; keys[2 * id + 1] = k1;
}

// B-fragment pack (unchanged layout): Bhi/Blo[((gct*8+kb)*64+lane)*8+j]
__global__ void pack_kernel(const float* __restrict__ W_hh,
                            const float* __restrict__ w_mu,
                            const float* __restrict__ w_ls,
                            unsigned short* __restrict__ Bhi,
                            unsigned short* __restrict__ Blo,
                            unsigned short* __restrict__ Bmu) {
  int idx = blockIdx.x * blockDim.x + threadIdx.x;
  if (idx < 65536) {
    int j = idx & 7, lane = (idx >> 3) & 63, kb = (idx >> 9) & 7, gct = idx >> 12;
    int k = kb * 16 + ((lane >> 5) << 3) + j;
    int g = (gct << 5) + (lane & 31);
    float w = W_hh[k * NG + g];
    unsigned short hi = f2bf(w);
    unsigned short lo = f2bf(w - bf2f(hi));
    Bhi[idx] = hi; Blo[idx] = lo;
  } else if (idx < 65536 + 4096) {
    int i2 = idx - 65536;
    int j = i2 & 7, lane = (i2 >> 3) & 63, kb = (i2 >> 9) & 7;
    int k = kb * 16 + ((lane >> 5) << 3) + j;
    int col = lane & 31;
    float v = (col == 0) ? w_mu[k] : (col == 1 ? w_ls[k] : 0.0f);
    Bmu[i2] = f2bf(v);
  }
}

// ------------------------------ main LSTM kernel ---------------------------
// RT=2 (mc): 512 thr = 8 waves, 64 rows; wave w: cg=w>>1, rt=w&1; 4 tiles.
// RT=1 (hist): 256 thr = 4 waves, 32 rows; wave w: cg=w, rt=0.
template<int RT, bool STOCH>
__launch_bounds__(RT * 256, RT)   // RT=2 -> cap 256 regs (2 waves/EU); RT=1 -> 512
__global__ void lstm_kernel(const float* __restrict__ ret,
                            const float* __restrict__ W_ih,
                            const float* __restrict__ bias,
                            const unsigned short* __restrict__ Bhi,
                            const unsigned short* __restrict__ Blo,
                            const unsigned short* __restrict__ Bmu,
                            const float* __restrict__ hin,
                            const float* __restrict__ cin,
                            float* __restrict__ hout,
                            float* __restrict__ cout,
                            const float* __restrict__ b_mu,
                            const float* __restrict__ b_ls,
                            const uint32_t* __restrict__ keys,
                            float* __restrict__ accum) {
  __shared__ unsigned short hfh[2][RT][HFN];
  __shared__ unsigned short hfl[2][RT][HFN];
  __shared__ float x_s[64];
  __shared__ float mu_s[64];
  __shared__ float ls_s[64];

  const int tid  = threadIdx.x;
  const int lane = tid & 63;
  const int w    = tid >> 6;
  const int cg   = (RT == 2) ? (w >> 1) : w;
  const int rt   = (RT == 2) ? (w & 1) : 0;
  const int hs   = lane >> 5;
  const int m    = lane & 31;
  const int col  = (cg << 5) + m;

  int s, b0;
  if (STOCH) { s = blockIdx.x >> 7; b0 = (blockIdx.x & 127) << 6; }
  else       { s = 0;               b0 = blockIdx.x << 5; }   // 32 rows (RT=1)

  float wih_r[4], bb_r[4];
#pragma unroll
  for (int gi = 0; gi < 4; ++gi) {
    wih_r[gi] = W_ih[(gi << 7) + col];
    bb_r[gi]  = bias[(gi << 7) + col];
  }
  const float bmu = b_mu[0], bls = b_ls[0];

  // swizzled frag offsets: write (per lane's col), read (per lane's m,hs)
  const int coff = (col >> 4) * SKB + ((col >> 3) & 1) * SHS + (col & 7);
  const int aoff = hs * SHS + m * 8;

  // Bmu frags preloaded once (STOCH only): 8 frags = 32 regs
  bfrag bmu_f[STOCH ? 8 : 1];
  if (STOCH) {
#pragma unroll
    for (int kb = 0; kb < 8; ++kb)
      bmu_f[kb] = *(const bfrag*)&Bmu[kb * 512 + lane * 8];
  }

  // ---- init h frags (buf 0) + c registers (this wave's rt tile only)
  float c_reg[16];
#pragma unroll
  for (int reg = 0; reg < 16; ++reg) {
    int row32 = (reg & 3) + ((reg >> 2) << 3) + (hs << 2);
    float hv = 0.0f, cv = 0.0f;
    if (STOCH) {
      int grow = b0 + (rt << 5) + row32;
      hv = hin[grow * HH + col];
      cv = cin[grow * HH + col];
    }
    c_reg[reg] = cv;
    unsigned short hi = f2bf(hv);
    unsigned short lo = f2bf(hv - bf2f(hi));
    hfh[0][rt][coff + row32 * 8] = hi;
    hfl[0][rt][coff + row32 * 8] = lo;
  }
  if (STOCH && tid < 64) x_s[tid] = ret[126 * NB + b0 + tid];
  float logw = 0.0f, outv = 0.0f;
  __syncthreads();

  const int nsteps = STOCH ? NSTEP : NHIST;
  int buf = 0;
#pragma unroll 1
  for (int t = 0; t < nsteps; ++t) {
    const int nbuf = buf ^ 1;

    // ---- C init: x*W_ih + b (fp32 exact)
    facc acc[4];
#pragma unroll
    for (int reg = 0; reg < 16; ++reg) {
      int row32 = (reg & 3) + ((reg >> 2) << 3) + (hs << 2);
      float xv;
      if (STOCH) xv = x_s[(rt << 5) + row32];
      else       xv = ret[t * NB + b0 + row32];
#pragma unroll
      for (int gi = 0; gi < 4; ++gi)
        acc[gi][reg] = fmaf(xv, wih_r[gi], bb_r[gi]);
    }

    // ---- gate matmul: 3-term split-bf16, 96 MFMAs/wave
#pragma unroll 2
    for (int kb = 0; kb < 8; ++kb) {
      bfrag ah = *(const bfrag*)&hfh[buf][rt][kb * SKB + aoff];
      bfrag al = *(const bfrag*)&hfl[buf][rt][kb * SKB + aoff];
      bfrag bh[4], bl[4];
#pragma unroll
      for (int gi = 0; gi < 4; ++gi) {
        const int off = ((((gi << 2) + cg) << 3) + kb) * 512 + lane * 8;
        bh[gi] = *(const bfrag*)&Bhi[off];
        bl[gi] = *(const bfrag*)&Blo[off];
      }
#pragma unroll
      for (int gi = 0; gi < 4; ++gi)
        acc[gi] = __builtin_amdgcn_mfma_f32_32x32x16_bf16(ah, bh[gi], acc[gi], 0, 0, 0);
#pragma unroll
      for (int gi = 0; gi < 4; ++gi)
        acc[gi] = __builtin_amdgcn_mfma_f32_32x32x16_bf16(al, bh[gi], acc[gi], 0, 0, 0);
#pragma unroll
      for (int gi = 0; gi < 4; ++gi)
        acc[gi] = __builtin_amdgcn_mfma_f32_32x32x16_bf16(ah, bl[gi], acc[gi], 0, 0, 0);
    }

    // ---- epilogue: cell update, conflict-free frag writes to nbuf
#pragma unroll
    for (int reg = 0; reg < 16; ++reg) {
      int row32 = (reg & 3) + ((reg >> 2) << 3) + (hs << 2);
      float ig = fast_sigmoid(acc[0][reg]);
      float fg = fast_sigmoid(acc[1][reg]);
      float gg = fast_tanh  (acc[2][reg]);
      float og = fast_sigmoid(acc[3][reg]);
      float c  = fmaf(fg, c_reg[reg], ig * gg);
      c_reg[reg] = c;
      float h  = og * fast_tanh(c);
      unsigned short hi = f2bf(h);
      unsigned short lo = f2bf(h - bf2f(hi));
      hfh[nbuf][rt][coff + row32 * 8] = hi;
      hfl[nbuf][rt][coff + row32 * 8] = lo;
      if (!STOCH && t == NHIST - 1)
        hout[(b0 + row32) * HH + col] = h;
    }
    __syncthreads();   // B1: nbuf writes visible; old-buf reads done

    if (STOCH) {
      // mu/ls matmul + RNG: redundantly on ALL waves (no serial section)
      facc am[RT];
#pragma unroll
      for (int rr = 0; rr < RT; ++rr)
#pragma unroll
        for (int e = 0; e < 16; ++e) am[rr][e] = 0.0f;
#pragma unroll
      for (int kb = 0; kb < 8; ++kb) {
#pragma unroll
        for (int rr = 0; rr < RT; ++rr) {
          const bfrag a0 = *(const bfrag*)&hfh[nbuf][rr][kb * SKB + aoff];
          am[rr] = __builtin_amdgcn_mfma_f32_32x32x16_bf16(a0, bmu_f[kb], am[rr], 0, 0, 0);
        }
      }
      if (m < 2) {   // benign same-value redundant writes across waves
        float* dst = (m == 0) ? mu_s : ls_s;
#pragma unroll
        for (int rr = 0; rr < RT; ++rr)
#pragma unroll
          for (int reg = 0; reg < 16; ++reg)
            dst[(rr << 5) + (reg & 3) + ((reg >> 2) << 3) + (hs << 2)] = am[rr][reg];
      }
      // same-wave LDS RAW: compiler inserts lgkmcnt wait; values identical
      float mu  = mu_s[lane] + bmu;
      float lsc = fminf(fmaxf(ls_s[lane] + bls, -5.0f), 2.0f);
      float sg  = __expf(lsc);
      uint32_t k0 = keys[2 * (s * NSTEP + t)];
      uint32_t k1 = keys[2 * (s * NSTEP + t) + 1];
      float z  = normal32(k0, k1, (uint32_t)(b0 + lane));
      float xn = fmaf(sg, z + 0.5f, mu);
      logw -= fmaf(0.5f, z, 0.125f);
      if (t == TCAP) outv = xn;
      x_s[lane] = xn;   // all waves write identical values
      __syncthreads();  // B2: x_s ready
    }
    buf = nbuf;
  }

  if (STOCH) {
    if (w == 0) {
      float wt = __expf(logw);
      float ow = outv * wt;
      int b = b0 + lane;
      atomicAdd(&accum[0 * NB + b], wt);
      atomicAdd(&accum[1 * NB + b], ow);
      atomicAdd(&accum[2 * NB + b], wt * wt);
      atomicAdd(&accum[3 * NB + b], ow * ow);
      atomicAdd(&accum[4 * NB + b], outv * wt * wt);
    }
  } else {
#pragma unroll
    for (int reg = 0; reg < 16; ++reg) {
      int row32 = (reg & 3) + ((reg >> 2) << 3) + (hs << 2);
      cout[(b0 + row32) * HH + col] = c_reg[reg];
    }
  }
}

// ------------------------------- final kernel ------------------------------
__global__ void final_kernel(const float* __restrict__ accum,
                             float* __restrict__ out) {
  int b = blockIdx.x * blockDim.x + threadIdx.x;
  if (b >= NB) return;
  float sw  = accum[0 * NB + b];
  float sm1 = accum[1 * NB + b];
  float sqw = accum[2 * NB + b];
  float sm2 = accum[3 * NB + b];
  float shm = accum[4 * NB + b];
  float mean = sm1 / sw;
  float sem = sm2 + sqw * mean * mean - 2.0f * shm * mean;
  sem = sqrtf(sem / (float)(NSAMP * (NSAMP - 1)));
  out[b] = mean;
  out[NB + b] = sem;
}

// ------------------------------- launcher ----------------------------------
extern "C" void kernel_launch(void* const* d_in, const int* in_sizes, int n_in,
                              void* d_out, int out_size, void* d_ws, size_t ws_size,
                              hipStream_t stream) {
  (void)in_sizes; (void)n_in; (void)out_size; (void)ws_size;
  const float* inp  = (const float*)d_in[0];
  const float* pert = (const float*)d_in[1];
  const float* W_ih = (const float*)d_in[2];
  const float* W_hh = (const float*)d_in[3];
  const float* bias = (const float*)d_in[4];
  const float* w_mu = (const float*)d_in[5];
  const float* b_mu = (const float*)d_in[6];
  const float* w_ls = (const float*)d_in[7];
  const float* b_ls = (const float*)d_in[8];

  char* ws = (char*)d_ws;
  float* ret = (float*)ws;        ws += (size_t)NRET * NB * sizeof(float);
  float* hh  = (float*)ws;        ws += (size_t)NB * HH * sizeof(float);
  float* cc  = (float*)ws;        ws += (size_t)NB * HH * sizeof(float);
  uint32_t* keys = (uint32_t*)ws; ws += (size_t)NSAMP * NSTEP * 2 * sizeof(uint32_t);
  float* accum = (float*)ws;      ws += (size_t)5 * NB * sizeof(float);
  unsigned short* Bhi = (unsigned short*)ws; ws += 65536 * sizeof(unsigned short);
  unsigned short* Blo = (unsigned short*)ws; ws += 65536 * sizeof(unsigned short);
  unsigned short* Bmu = (unsigned short*)ws; ws += 4096 * sizeof(unsigned short);

  hipMemsetAsync(accum, 0, (size_t)5 * NB * sizeof(float), stream);
  returns_kernel<<<(NRET * NB + 255) / 256, 256, 0, stream>>>(inp, pert, ret);
  keys_kernel<<<(NSAMP * NSTEP + 255) / 256, 256, 0, stream>>>(keys);
  pack_kernel<<<(65536 + 4096) / 256, 256, 0, stream>>>(W_hh, w_mu, w_ls, Bhi, Blo, Bmu);
  lstm_kernel<1, false><<<NB / 32, 256, 0, stream>>>(ret, W_ih, bias, Bhi, Blo, Bmu,
      nullptr, nullptr, hh, cc, b_mu, b_ls, keys, nullptr);
  lstm_kernel<2, true><<<NSAMP * (NB / 64), 512, 0, stream>>>(ret, W_ih, bias, Bhi, Blo, Bmu,
      hh, cc, nullptr, nullptr, b_mu, b_ls, keys, accum);
  final_kernel<<<NB / 256, 256, 0, stream>>>(accum, (float*)d_out);
}

// Round 8
// 15427.841 us; speedup vs baseline: 2.0428x; 2.0428x over previous
//
#include <hip/hip_runtime.h>
#include <stdint.h>
#include <math.h>

// ---------------------------------------------------------------------------
// Round 8: R6 block structure (64 rows, 4 waves x 8 acc tiles = 128 AGPR) at
// (256,2) = 2 blocks/CU, with the arch-VGPR working set engineered under the
// empirical 128-reg cap of (X,2) bounds:
//  * kb loop unroll 1, B loaded per GATE-PAIR (16 live B regs, was 32).
//  * wave-0-only mu/RNG (R6 style; R7's all-wave version multiplied VALU).
//  * R7's LDS swizzle kept (conflicts 4.29e8 -> 1.31e8).
//  * one B-load per tile per block (R7 duplicated x2 across waves).
// Arch estimate ~102 regs -> no spills; AGPR 128; total = 256 budget exactly.
// ---------------------------------------------------------------------------

#define HH     128
#define NG     512
#define NB     8192
#define NSAMP  100
#define NSTEP  20
#define TCAP   18
#define NHIST  126
#define NRET   127

using bfrag = __attribute__((ext_vector_type(8))) short;   // 8 bf16 = 4 VGPRs
using facc  = __attribute__((ext_vector_type(16))) float;  // 16 f32 acc

// LDS frag strides (shorts): per-(kb,hs) region 264 (8 pad), per-kb 528.
#define SHS 264
#define SKB 528
#define HFN 4224   // 8 kb * 528

// ----------------------------- threefry2x32 --------------------------------
__device__ __forceinline__ void tf2x32(uint32_t k0, uint32_t k1,
                                       uint32_t x0, uint32_t x1,
                                       uint32_t &y0, uint32_t &y1) {
  uint32_t ks2 = k0 ^ k1 ^ 0x1BD11BDAu;
  x0 += k0; x1 += k1;
#define RR(r) { x0 += x1; x1 = (x1 << (r)) | (x1 >> (32 - (r))); x1 ^= x0; }
  RR(13) RR(15) RR(26) RR(6)   x0 += k1;  x1 += ks2 + 1u;
  RR(17) RR(29) RR(16) RR(24)  x0 += ks2; x1 += k0  + 2u;
  RR(13) RR(15) RR(26) RR(6)   x0 += k0;  x1 += k1  + 3u;
  RR(17) RR(29) RR(16) RR(24)  x0 += k1;  x1 += ks2 + 4u;
  RR(13) RR(15) RR(26) RR(6)   x0 += ks2; x1 += k0  + 5u;
#undef RR
  y0 = x0; y1 = x1;
}

__device__ __forceinline__ float erfinv32(float x) {
  float w = -__logf(fmaxf(1.0f - x * x, 1e-37f));
  float p;
  if (w < 5.0f) {
    w = w - 2.5f;
    p = 2.81022636e-08f;
    p = fmaf(p, w, 3.43273939e-07f);
    p = fmaf(p, w, -3.5233877e-06f);
    p = fmaf(p, w, -4.39150654e-06f);
    p = fmaf(p, w, 0.00021858087f);
    p = fmaf(p, w, -0.00125372503f);
    p = fmaf(p, w, -0.00417768164f);
    p = fmaf(p, w, 0.246640727f);
    p = fmaf(p, w, 1.50140941f);
  } else {
    w = sqrtf(w) - 3.0f;
    p = -0.000200214257f;
    p = fmaf(p, w, 0.000100950558f);
    p = fmaf(p, w, 0.00134934322f);
    p = fmaf(p, w, -0.00367342844f);
    p = fmaf(p, w, 0.00573950773f);
    p = fmaf(p, w, -0.0076224613f);
    p = fmaf(p, w, 0.00943887047f);
    p = fmaf(p, w, 1.00167406f);
    p = fmaf(p, w, 2.83297682f);
  }
  return p * x;
}

__device__ __forceinline__ float normal32(uint32_t k0, uint32_t k1, uint32_t idx) {
  uint32_t y0, y1;
  tf2x32(k0, k1, 0u, idx, y0, y1);
  uint32_t bits = y0 ^ y1;
  float f = __uint_as_float((bits >> 9) | 0x3f800000u) - 1.0f;
  const float lo = __uint_as_float(0xBF7FFFFFu);
  float u = fmaxf(lo, f * 2.0f + lo);
  return 1.41421356f * erfinv32(u);
}

__device__ __forceinline__ float fast_sigmoid(float x) {
  return __builtin_amdgcn_rcpf(1.0f + __expf(-x));
}
__device__ __forceinline__ float fast_tanh(float x) {
  return 1.0f - 2.0f * __builtin_amdgcn_rcpf(1.0f + __expf(2.0f * x));
}

__device__ __forceinline__ unsigned short f2bf(float x) {
  uint32_t u = __float_as_uint(x);
  uint32_t r = u + 0x7fffu + ((u >> 16) & 1u);
  return (unsigned short)(r >> 16);
}
__device__ __forceinline__ float bf2f(unsigned short h) {
  return __uint_as_float(((uint32_t)h) << 16);
}

// ------------------------------- small kernels -----------------------------
__global__ void returns_kernel(const float* __restrict__ inp,
                               const float* __restrict__ pert,
                               float* __restrict__ ret) {
  int i = blockIdx.x * blockDim.x + threadIdx.x;
  if (i >= NRET * NB) return;
  int s = i / NB, b = i - s * NB;
  float p0 = inp[s * NB + b] * (1.0f + pert[s * NB + b]);
  float p1 = inp[(s + 1) * NB + b] * (1.0f + pert[(s + 1) * NB + b]);
  ret[i] = p1 - p0;
}

__global__ void keys_kernel(uint32_t* __restrict__ keys) {
  int id = blockIdx.x * blockDim.x + threadIdx.x;
  if (id >= NSAMP * NSTEP) return;
  int s = id / NSTEP, t = id - s * NSTEP;
  uint32_t sk0, sk1, k0, k1;
  tf2x32(0u, 42u, 0u, (uint32_t)s, sk0, sk1);
  tf2x32(sk0, sk1, 0u, (uint32_t)t, k0, k1);
  keys[2 * id] = k0; keys[2 * id + 1] = k1;
}

// B-fragment pack: Bhi/Blo[((gct*8+kb)*64+lane)*8+j]
//   k = kb*16 + 8*(lane>>5) + j, g = 32*gct + (lane&31).
__global__ void pack_kernel(const float* __restrict__ W_hh,
                            const float* __restrict__ w_mu,
                            const float* __restrict__ w_ls,
                            unsigned short* __restrict__ Bhi,
                            unsigned short* __restrict__ Blo,
                            unsigned short* __restrict__ Bmu) {
  int idx = blockIdx.x * blockDim.x + threadIdx.x;
  if (idx < 65536) {
    int j = idx & 7, lane = (idx >> 3) & 63, kb = (idx >> 9) & 7, gct = idx >> 12;
    int k = kb * 16 + ((lane >> 5) << 3) + j;
    int g = (gct << 5) + (lane & 31);
    float w = W_hh[k * NG + g];
    unsigned short hi = f2bf(w);
    unsigned short lo = f2bf(w - bf2f(hi));
    Bhi[idx] = hi; Blo[idx] = lo;
  } else if (idx < 65536 + 4096) {
    int i2 = idx - 65536;
    int j = i2 & 7, lane = (i2 >> 3) & 63, kb = (i2 >> 9) & 7;
    int k = kb * 16 + ((lane >> 5) << 3) + j;
    int col = lane & 31;
    float v = (col == 0) ? w_mu[k] : (col == 1 ? w_ls[k] : 0.0f);
    Bmu[i2] = f2bf(v);
  }
}

// ------------------------------ main LSTM kernel ---------------------------
// 256 thr = 4 waves; wave w = hidden-col group cg; each wave owns RT row
// tiles x 4 gates (RT=2: 64 rows, acc 128 AGPR; RT=1: 32 rows, acc 64).
template<int RT, bool STOCH, int MINW>
__launch_bounds__(256, MINW)
__global__ void lstm_kernel(const float* __restrict__ ret,
                            const float* __restrict__ W_ih,
                            const float* __restrict__ bias,
                            const unsigned short* __restrict__ Bhi,
                            const unsigned short* __restrict__ Blo,
                            const unsigned short* __restrict__ Bmu,
                            const float* __restrict__ hin,
                            const float* __restrict__ cin,
                            float* __restrict__ hout,
                            float* __restrict__ cout,
                            const float* __restrict__ b_mu,
                            const float* __restrict__ b_ls,
                            const uint32_t* __restrict__ keys,
                            float* __restrict__ accum) {
  __shared__ unsigned short hfh[2][RT][HFN];
  __shared__ unsigned short hfl[2][RT][HFN];
  __shared__ float x_s[32 * RT];
  __shared__ float mu_s[32 * RT];
  __shared__ float ls_s[32 * RT];

  const int tid  = threadIdx.x;
  const int lane = tid & 63;
  const int cg   = tid >> 6;          // wave id = hidden-col group
  const int hs   = lane >> 5;
  const int m    = lane & 31;
  const int col  = (cg << 5) + m;

  int s, b0;
  if (STOCH) { s = blockIdx.x >> 7; b0 = (blockIdx.x & 127) << 6; }
  else       { s = 0;               b0 = blockIdx.x * (32 * RT); }

  float wih_r[4], bb_r[4];
#pragma unroll
  for (int gi = 0; gi < 4; ++gi) {
    wih_r[gi] = W_ih[(gi << 7) + col];
    bb_r[gi]  = bias[(gi << 7) + col];
  }
  const float bmu = b_mu[0], bls = b_ls[0];

  // swizzled frag offsets: write (lane's col), read (lane's m,hs)
  const int coff = (col >> 4) * SKB + ((col >> 3) & 1) * SHS + (col & 7);
  const int aoff = hs * SHS + m * 8;

  // ---- init h frags (buf 0) + c registers
  float c_reg[RT][16];
#pragma unroll
  for (int rr = 0; rr < RT; ++rr) {
#pragma unroll
    for (int reg = 0; reg < 16; ++reg) {
      int row32 = (reg & 3) + ((reg >> 2) << 3) + (hs << 2);
      float hv = 0.0f, cv = 0.0f;
      if (STOCH) {
        int grow = b0 + (rr << 5) + row32;
        hv = hin[grow * HH + col];
        cv = cin[grow * HH + col];
      }
      c_reg[rr][reg] = cv;
      unsigned short hi = f2bf(hv);
      unsigned short lo = f2bf(hv - bf2f(hi));
      hfh[0][rr][coff + row32 * 8] = hi;
      hfl[0][rr][coff + row32 * 8] = lo;
    }
  }
  if (STOCH && tid < 32 * RT) x_s[tid] = ret[126 * NB + b0 + tid];
  float logw = 0.0f, outv = 0.0f;
  __syncthreads();

  const int nsteps = STOCH ? NSTEP : NHIST;
  int buf = 0;
#pragma unroll 1
  for (int t = 0; t < nsteps; ++t) {
    const int nbuf = buf ^ 1;

    // ---- C init: x*W_ih + b (fp32 exact)
    facc acc[4 * RT];
#pragma unroll
    for (int rr = 0; rr < RT; ++rr) {
#pragma unroll
      for (int reg = 0; reg < 16; ++reg) {
        int row32 = (reg & 3) + ((reg >> 2) << 3) + (hs << 2);
        float xv;
        if (STOCH) xv = x_s[(rr << 5) + row32];
        else       xv = ret[t * NB + b0 + (rr << 5) + row32];
#pragma unroll
        for (int gi = 0; gi < 4; ++gi)
          acc[gi * RT + rr][reg] = fmaf(xv, wih_r[gi], bb_r[gi]);
      }
    }

    // ---- gate matmul: 3-term split-bf16; B loaded per gate-pair (16 regs)
#pragma unroll 1
    for (int kb = 0; kb < 8; ++kb) {
      bfrag ah[RT], al[RT];
#pragma unroll
      for (int rr = 0; rr < RT; ++rr) {
        ah[rr] = *(const bfrag*)&hfh[buf][rr][kb * SKB + aoff];
        al[rr] = *(const bfrag*)&hfl[buf][rr][kb * SKB + aoff];
      }
#pragma unroll
      for (int gp = 0; gp < 2; ++gp) {
        const int g0 = 2 * gp, g1 = 2 * gp + 1;
        const int off0 = ((((g0 << 2) + cg) << 3) + kb) * 512 + lane * 8;
        const int off1 = ((((g1 << 2) + cg) << 3) + kb) * 512 + lane * 8;
        bfrag bh0 = *(const bfrag*)&Bhi[off0];
        bfrag bl0 = *(const bfrag*)&Blo[off0];
        bfrag bh1 = *(const bfrag*)&Bhi[off1];
        bfrag bl1 = *(const bfrag*)&Blo[off1];
#pragma unroll
        for (int rr = 0; rr < RT; ++rr) {
          acc[g0*RT+rr] = __builtin_amdgcn_mfma_f32_32x32x16_bf16(ah[rr], bh0, acc[g0*RT+rr], 0, 0, 0);
          acc[g1*RT+rr] = __builtin_amdgcn_mfma_f32_32x32x16_bf16(ah[rr], bh1, acc[g1*RT+rr], 0, 0, 0);
        }
#pragma unroll
        for (int rr = 0; rr < RT; ++rr) {
          acc[g0*RT+rr] = __builtin_amdgcn_mfma_f32_32x32x16_bf16(al[rr], bh0, acc[g0*RT+rr], 0, 0, 0);
          acc[g1*RT+rr] = __builtin_amdgcn_mfma_f32_32x32x16_bf16(al[rr], bh1, acc[g1*RT+rr], 0, 0, 0);
        }
#pragma unroll
        for (int rr = 0; rr < RT; ++rr) {
          acc[g0*RT+rr] = __builtin_amdgcn_mfma_f32_32x32x16_bf16(ah[rr], bl0, acc[g0*RT+rr], 0, 0, 0);
          acc[g1*RT+rr] = __builtin_amdgcn_mfma_f32_32x32x16_bf16(ah[rr], bl1, acc[g1*RT+rr], 0, 0, 0);
        }
      }
    }

    // ---- epilogue: cell update, swizzled (low-conflict) frag writes
#pragma unroll
    for (int rr = 0; rr < RT; ++rr) {
#pragma unroll
      for (int reg = 0; reg < 16; ++reg) {
        int row32 = (reg & 3) + ((reg >> 2) << 3) + (hs << 2);
        float ig = fast_sigmoid(acc[0 * RT + rr][reg]);
        float fg = fast_sigmoid(acc[1 * RT + rr][reg]);
        float gg = fast_tanh  (acc[2 * RT + rr][reg]);
        float og = fast_sigmoid(acc[3 * RT + rr][reg]);
        float c  = fmaf(fg, c_reg[rr][reg], ig * gg);
        c_reg[rr][reg] = c;
        float h  = og * fast_tanh(c);
        unsigned short hi = f2bf(h);
        unsigned short lo = f2bf(h - bf2f(hi));
        hfh[nbuf][rr][coff + row32 * 8] = hi;
        hfl[nbuf][rr][coff + row32 * 8] = lo;
        if (!STOCH && t == NHIST - 1)
          hout[(b0 + (rr << 5) + row32) * HH + col] = h;
      }
    }
    __syncthreads();   // B1: nbuf writes visible; old-buf reads done

    if (STOCH) {
      if (tid < 64) {   // wave 0: mu/ls MFMA + RNG + x update
        facc am[RT];
#pragma unroll
        for (int rr = 0; rr < RT; ++rr)
#pragma unroll
          for (int e = 0; e < 16; ++e) am[rr][e] = 0.0f;
#pragma unroll 1
        for (int kb = 0; kb < 8; ++kb) {
          const bfrag bm = *(const bfrag*)&Bmu[kb * 512 + lane * 8];
#pragma unroll
          for (int rr = 0; rr < RT; ++rr) {
            const bfrag a0 = *(const bfrag*)&hfh[nbuf][rr][kb * SKB + aoff];
            am[rr] = __builtin_amdgcn_mfma_f32_32x32x16_bf16(a0, bm, am[rr], 0, 0, 0);
          }
        }
        if (m < 2) {
          float* dst = (m == 0) ? mu_s : ls_s;
#pragma unroll
          for (int rr = 0; rr < RT; ++rr)
#pragma unroll
            for (int reg = 0; reg < 16; ++reg)
              dst[(rr << 5) + (reg & 3) + ((reg >> 2) << 3) + (hs << 2)] = am[rr][reg];
        }
        // same-wave LDS RAW: compiler inserts lgkmcnt wait
        float mu  = mu_s[lane] + bmu;
        float lsc = fminf(fmaxf(ls_s[lane] + bls, -5.0f), 2.0f);
        float sg  = __expf(lsc);
        uint32_t k0 = keys[2 * (s * NSTEP + t)];
        uint32_t k1 = keys[2 * (s * NSTEP + t) + 1];
        float z  = normal32(k0, k1, (uint32_t)(b0 + lane));
        float xn = fmaf(sg, z + 0.5f, mu);
        logw -= fmaf(0.5f, z, 0.125f);
        if (t == TCAP) outv = xn;
        x_s[lane] = xn;
      }
      __syncthreads();  // B2: x_s ready
    }
    buf = nbuf;
  }

  if (STOCH) {
    if (tid < 64) {
      float wt = __expf(logw);
      float ow = outv * wt;
      int b = b0 + lane;
      atomicAdd(&accum[0 * NB + b], wt);
      atomicAdd(&accum[1 * NB + b], ow);
      atomicAdd(&accum[2 * NB + b], wt * wt);
      atomicAdd(&accum[3 * NB + b], ow * ow);
      atomicAdd(&accum[4 * NB + b], outv * wt * wt);
    }
  } else {
#pragma unroll
    for (int rr = 0; rr < RT; ++rr)
#pragma unroll
      for (int reg = 0; reg < 16; ++reg) {
        int row32 = (reg & 3) + ((reg >> 2) << 3) + (hs << 2);
        cout[(b0 + (rr << 5) + row32) * HH + col] = c_reg[rr][reg];
      }
  }
}

// ------------------------------- final kernel ------------------------------
__global__ void final_kernel(const float* __restrict__ accum,
                             float* __restrict__ out) {
  int b = blockIdx.x * blockDim.x + threadIdx.x;
  if (b >= NB) return;
  float sw  = accum[0 * NB + b];
  float sm1 = accum[1 * NB + b];
  float sqw = accum[2 * NB + b];
  float sm2 = accum[3 * NB + b];
  float shm = accum[4 * NB + b];
  float mean = sm1 / sw;
  float sem = sm2 + sqw * mean * mean - 2.0f * shm * mean;
  sem = sqrtf(sem / (float)(NSAMP * (NSAMP - 1)));
  out[b] = mean;
  out[NB + b] = sem;
}

// ------------------------------- launcher ----------------------------------
extern "C" void kernel_launch(void* const* d_in, const int* in_sizes, int n_in,
                              void* d_out, int out_size, void* d_ws, size_t ws_size,
                              hipStream_t stream) {
  (void)in_sizes; (void)n_in; (void)out_size; (void)ws_size;
  const float* inp  = (const float*)d_in[0];
  const float* pert = (const float*)d_in[1];
  const float* W_ih = (const float*)d_in[2];
  const float* W_hh = (const float*)d_in[3];
  const float* bias = (const float*)d_in[4];
  const float* w_mu = (const float*)d_in[5];
  const float* b_mu = (const float*)d_in[6];
  const float* w_ls = (const float*)d_in[7];
  const float* b_ls = (const float*)d_in[8];

  char* ws = (char*)d_ws;
  float* ret = (float*)ws;        ws += (size_t)NRET * NB * sizeof(float);
  float* hh  = (float*)ws;        ws += (size_t)NB * HH * sizeof(float);
  float* cc  = (float*)ws;        ws += (size_t)NB * HH * sizeof(float);
  uint32_t* keys = (uint32_t*)ws; ws += (size_t)NSAMP * NSTEP * 2 * sizeof(uint32_t);
  float* accum = (float*)ws;      ws += (size_t)5 * NB * sizeof(float);
  unsigned short* Bhi = (unsigned short*)ws; ws += 65536 * sizeof(unsigned short);
  unsigned short* Blo = (unsigned short*)ws; ws += 65536 * sizeof(unsigned short);
  unsigned short* Bmu = (unsigned short*)ws; ws += 4096 * sizeof(unsigned short);

  hipMemsetAsync(accum, 0, (size_t)5 * NB * sizeof(float), stream);
  returns_kernel<<<(NRET * NB + 255) / 256, 256, 0, stream>>>(inp, pert, ret);
  keys_kernel<<<(NSAMP * NSTEP + 255) / 256, 256, 0, stream>>>(keys);
  pack_kernel<<<(65536 + 4096) / 256, 256, 0, stream>>>(W_hh, w_mu, w_ls, Bhi, Blo, Bmu);
  lstm_kernel<1, false, 1><<<NB / 32, 256, 0, stream>>>(ret, W_ih, bias, Bhi, Blo, Bmu,
      nullptr, nullptr, hh, cc, b_mu, b_ls, keys, nullptr);
  lstm_kernel<2, true, 2><<<NSAMP * (NB / 64), 256, 0, stream>>>(ret, W_ih, bias, Bhi, Blo, Bmu,
      hh, cc, nullptr, nullptr, b_mu, b_ls, keys, accum);
  final_kernel<<<NB / 256, 256, 0, stream>>>(accum, (float*)d_out);
}

// Round 9
// 14675.662 us; speedup vs baseline: 2.1475x; 1.0513x over previous
//
#include <hip/hip_runtime.h>
#include <stdint.h>
#include <math.h>

// ---------------------------------------------------------------------------
// Round 9: R7's 512-thread tiling with the launch-bounds lesson applied.
// Evidence across R3-R8: any __launch_bounds__(X,2) pins VGPR_Count=128 and
// spills (WRITE 2.2-2.9 GB scratch -> L2 eviction of the 256 KB B table);
// any (X,1) config allocates freely and never spills. So occupancy comes
// from BLOCK SIZE: 512 thr = 8 waves forces 2 waves/SIMD co-residency,
// capping the compiler at 256 unified regs -> no spill (wave needs ~190:
// 64 AGPR acc + ~125 arch) AND 2 waves/SIMD latency hiding.
//  * wave w = (cg=w>>1, rt=w&1): 4 acc tiles (2 gates... 4 gates x 1 rt).
//  * wave-0-only mu/RNG (R8 style, am[2] both row tiles).
//  * LDS swizzle kept (conflict-free frag writes).
//  * B rt-duplication accepted: 2x L2 traffic, ~26 TB/s at 5 ms, under the
//    36.9 TB/s measured L2 ceiling.
// ---------------------------------------------------------------------------

#define HH     128
#define NG     512
#define NB     8192
#define NSAMP  100
#define NSTEP  20
#define TCAP   18
#define NHIST  126
#define NRET   127

using bfrag = __attribute__((ext_vector_type(8))) short;   // 8 bf16 = 4 VGPRs
using facc  = __attribute__((ext_vector_type(16))) float;  // 16 f32 acc

// LDS frag strides (shorts): per-(kb,hs) region 264 (8 pad), per-kb 528.
#define SHS 264
#define SKB 528
#define HFN 4224   // 8 kb * 528

// ----------------------------- threefry2x32 --------------------------------
__device__ __forceinline__ void tf2x32(uint32_t k0, uint32_t k1,
                                       uint32_t x0, uint32_t x1,
                                       uint32_t &y0, uint32_t &y1) {
  uint32_t ks2 = k0 ^ k1 ^ 0x1BD11BDAu;
  x0 += k0; x1 += k1;
#define RR(r) { x0 += x1; x1 = (x1 << (r)) | (x1 >> (32 - (r))); x1 ^= x0; }
  RR(13) RR(15) RR(26) RR(6)   x0 += k1;  x1 += ks2 + 1u;
  RR(17) RR(29) RR(16) RR(24)  x0 += ks2; x1 += k0  + 2u;
  RR(13) RR(15) RR(26) RR(6)   x0 += k0;  x1 += k1  + 3u;
  RR(17) RR(29) RR(16) RR(24)  x0 += k1;  x1 += ks2 + 4u;
  RR(13) RR(15) RR(26) RR(6)   x0 += ks2; x1 += k0  + 5u;
#undef RR
  y0 = x0; y1 = x1;
}

__device__ __forceinline__ float erfinv32(float x) {
  float w = -__logf(fmaxf(1.0f - x * x, 1e-37f));
  float p;
  if (w < 5.0f) {
    w = w - 2.5f;
    p = 2.81022636e-08f;
    p = fmaf(p, w, 3.43273939e-07f);
    p = fmaf(p, w, -3.5233877e-06f);
    p = fmaf(p, w, -4.39150654e-06f);
    p = fmaf(p, w, 0.00021858087f);
    p = fmaf(p, w, -0.00125372503f);
    p = fmaf(p, w, -0.00417768164f);
    p = fmaf(p, w, 0.246640727f);
    p = fmaf(p, w, 1.50140941f);
  } else {
    w = sqrtf(w) - 3.0f;
    p = -0.000200214257f;
    p = fmaf(p, w, 0.000100950558f);
    p = fmaf(p, w, 0.00134934322f);
    p = fmaf(p, w, -0.00367342844f);
    p = fmaf(p, w, 0.00573950773f);
    p = fmaf(p, w, -0.0076224613f);
    p = fmaf(p, w, 0.00943887047f);
    p = fmaf(p, w, 1.00167406f);
    p = fmaf(p, w, 2.83297682f);
  }
  return p * x;
}

__device__ __forceinline__ float normal32(uint32_t k0, uint32_t k1, uint32_t idx) {
  uint32_t y0, y1;
  tf2x32(k0, k1, 0u, idx, y0, y1);
  uint32_t bits = y0 ^ y1;
  float f = __uint_as_float((bits >> 9) | 0x3f800000u) - 1.0f;
  const float lo = __uint_as_float(0xBF7FFFFFu);
  float u = fmaxf(lo, f * 2.0f + lo);
  return 1.41421356f * erfinv32(u);
}

__device__ __forceinline__ float fast_sigmoid(float x) {
  return __builtin_amdgcn_rcpf(1.0f + __expf(-x));
}
__device__ __forceinline__ float fast_tanh(float x) {
  return 1.0f - 2.0f * __builtin_amdgcn_rcpf(1.0f + __expf(2.0f * x));
}

__device__ __forceinline__ unsigned short f2bf(float x) {
  uint32_t u = __float_as_uint(x);
  uint32_t r = u + 0x7fffu + ((u >> 16) & 1u);
  return (unsigned short)(r >> 16);
}
__device__ __forceinline__ float bf2f(unsigned short h) {
  return __uint_as_float(((uint32_t)h) << 16);
}

// ------------------------------- small kernels -----------------------------
__global__ void returns_kernel(const float* __restrict__ inp,
                               const float* __restrict__ pert,
                               float* __restrict__ ret) {
  int i = blockIdx.x * blockDim.x + threadIdx.x;
  if (i >= NRET * NB) return;
  int s = i / NB, b = i - s * NB;
  float p0 = inp[s * NB + b] * (1.0f + pert[s * NB + b]);
  float p1 = inp[(s + 1) * NB + b] * (1.0f + pert[(s + 1) * NB + b]);
  ret[i] = p1 - p0;
}

__global__ void keys_kernel(uint32_t* __restrict__ keys) {
  int id = blockIdx.x * blockDim.x + threadIdx.x;
  if (id >= NSAMP * NSTEP) return;
  int s = id / NSTEP, t = id - s * NSTEP;
  uint32_t sk0, sk1, k0, k1;
  tf2x32(0u, 42u, 0u, (uint32_t)s, sk0, sk1);
  tf2x32(sk0, sk1, 0u, (uint32_t)t, k0, k1);
  keys[2 * id] = k0; keys[2 * id + 1] = k1;
}

// B-fragment pack: Bhi/Blo[((gct*8+kb)*64+lane)*8+j]
//   k = kb*16 + 8*(lane>>5) + j, g = 32*gct + (lane&31).
__global__ void pack_kernel(const float* __restrict__ W_hh,
                            const float* __restrict__ w_mu,
                            const float* __restrict__ w_ls,
                            unsigned short* __restrict__ Bhi,
                            unsigned short* __restrict__ Blo,
                            unsigned short* __restrict__ Bmu) {
  int idx = blockIdx.x * blockDim.x + threadIdx.x;
  if (idx < 65536) {
    int j = idx & 7, lane = (idx >> 3) & 63, kb = (idx >> 9) & 7, gct = idx >> 12;
    int k = kb * 16 + ((lane >> 5) << 3) + j;
    int g = (gct << 5) + (lane & 31);
    float w = W_hh[k * NG + g];
    unsigned short hi = f2bf(w);
    unsigned short lo = f2bf(w - bf2f(hi));
    Bhi[idx] = hi; Blo[idx] = lo;
  } else if (idx < 65536 + 4096) {
    int i2 = idx - 65536;
    int j = i2 & 7, lane = (i2 >> 3) & 63, kb = (i2 >> 9) & 7;
    int k = kb * 16 + ((lane >> 5) << 3) + j;
    int col = lane & 31;
    float v = (col == 0) ? w_mu[k] : (col == 1 ? w_ls[k] : 0.0f);
    Bmu[i2] = f2bf(v);
  }
}

// ------------------------------ main LSTM kernel ---------------------------
// RT=2 (mc): 512 thr = 8 waves, 64 rows; wave w: cg=w>>1, rt=w&1; 4 tiles
//   (64 AGPR acc). __launch_bounds__(512,1): block forces 2 waves/SIMD ->
//   256 unified regs cap -> no spill, 2-wave latency hiding.
// RT=1 (hist): 256 thr = 4 waves, 32 rows; wave w: cg=w, rt=0; (256,1).
template<int RT, bool STOCH>
__launch_bounds__(RT * 256, 1)
__global__ void lstm_kernel(const float* __restrict__ ret,
                            const float* __restrict__ W_ih,
                            const float* __restrict__ bias,
                            const unsigned short* __restrict__ Bhi,
                            const unsigned short* __restrict__ Blo,
                            const unsigned short* __restrict__ Bmu,
                            const float* __restrict__ hin,
                            const float* __restrict__ cin,
                            float* __restrict__ hout,
                            float* __restrict__ cout,
                            const float* __restrict__ b_mu,
                            const float* __restrict__ b_ls,
                            const uint32_t* __restrict__ keys,
                            float* __restrict__ accum) {
  __shared__ unsigned short hfh[2][RT][HFN];
  __shared__ unsigned short hfl[2][RT][HFN];
  __shared__ float x_s[64];
  __shared__ float mu_s[64];
  __shared__ float ls_s[64];

  const int tid  = threadIdx.x;
  const int lane = tid & 63;
  const int w    = tid >> 6;
  const int cg   = (RT == 2) ? (w >> 1) : w;
  const int rt   = (RT == 2) ? (w & 1) : 0;
  const int hs   = lane >> 5;
  const int m    = lane & 31;
  const int col  = (cg << 5) + m;

  int s, b0;
  if (STOCH) { s = blockIdx.x >> 7; b0 = (blockIdx.x & 127) << 6; }
  else       { s = 0;               b0 = blockIdx.x << 5; }   // 32 rows (RT=1)

  float wih_r[4], bb_r[4];
#pragma unroll
  for (int gi = 0; gi < 4; ++gi) {
    wih_r[gi] = W_ih[(gi << 7) + col];
    bb_r[gi]  = bias[(gi << 7) + col];
  }
  const float bmu = b_mu[0], bls = b_ls[0];

  // swizzled frag offsets: write (lane's col), read (lane's m,hs)
  const int coff = (col >> 4) * SKB + ((col >> 3) & 1) * SHS + (col & 7);
  const int aoff = hs * SHS + m * 8;

  // ---- init h frags (buf 0) + c registers (this wave's rt tile)
  float c_reg[16];
#pragma unroll
  for (int reg = 0; reg < 16; ++reg) {
    int row32 = (reg & 3) + ((reg >> 2) << 3) + (hs << 2);
    float hv = 0.0f, cv = 0.0f;
    if (STOCH) {
      int grow = b0 + (rt << 5) + row32;
      hv = hin[grow * HH + col];
      cv = cin[grow * HH + col];
    }
    c_reg[reg] = cv;
    unsigned short hi = f2bf(hv);
    unsigned short lo = f2bf(hv - bf2f(hi));
    hfh[0][rt][coff + row32 * 8] = hi;
    hfl[0][rt][coff + row32 * 8] = lo;
  }
  if (STOCH && tid < 64) x_s[tid] = ret[126 * NB + b0 + tid];
  float logw = 0.0f, outv = 0.0f;
  __syncthreads();

  const int nsteps = STOCH ? NSTEP : NHIST;
  int buf = 0;
#pragma unroll 1
  for (int t = 0; t < nsteps; ++t) {
    const int nbuf = buf ^ 1;

    // ---- C init: x*W_ih + b (fp32 exact)
    facc acc[4];
#pragma unroll
    for (int reg = 0; reg < 16; ++reg) {
      int row32 = (reg & 3) + ((reg >> 2) << 3) + (hs << 2);
      float xv;
      if (STOCH) xv = x_s[(rt << 5) + row32];
      else       xv = ret[t * NB + b0 + row32];
#pragma unroll
      for (int gi = 0; gi < 4; ++gi)
        acc[gi][reg] = fmaf(xv, wih_r[gi], bb_r[gi]);
    }

    // ---- gate matmul: 3-term split-bf16, 96 MFMAs/wave
#pragma unroll 2
    for (int kb = 0; kb < 8; ++kb) {
      bfrag ah = *(const bfrag*)&hfh[buf][rt][kb * SKB + aoff];
      bfrag al = *(const bfrag*)&hfl[buf][rt][kb * SKB + aoff];
      bfrag bh[4], bl[4];
#pragma unroll
      for (int gi = 0; gi < 4; ++gi) {
        const int off = ((((gi << 2) + cg) << 3) + kb) * 512 + lane * 8;
        bh[gi] = *(const bfrag*)&Bhi[off];
        bl[gi] = *(const bfrag*)&Blo[off];
      }
#pragma unroll
      for (int gi = 0; gi < 4; ++gi)
        acc[gi] = __builtin_amdgcn_mfma_f32_32x32x16_bf16(ah, bh[gi], acc[gi], 0, 0, 0);
#pragma unroll
      for (int gi = 0; gi < 4; ++gi)
        acc[gi] = __builtin_amdgcn_mfma_f32_32x32x16_bf16(al, bh[gi], acc[gi], 0, 0, 0);
#pragma unroll
      for (int gi = 0; gi < 4; ++gi)
        acc[gi] = __builtin_amdgcn_mfma_f32_32x32x16_bf16(ah, bl[gi], acc[gi], 0, 0, 0);
    }

    // ---- epilogue: cell update, swizzled (conflict-free) frag writes
#pragma unroll
    for (int reg = 0; reg < 16; ++reg) {
      int row32 = (reg & 3) + ((reg >> 2) << 3) + (hs << 2);
      float ig = fast_sigmoid(acc[0][reg]);
      float fg = fast_sigmoid(acc[1][reg]);
      float gg = fast_tanh  (acc[2][reg]);
      float og = fast_sigmoid(acc[3][reg]);
      float c  = fmaf(fg, c_reg[reg], ig * gg);
      c_reg[reg] = c;
      float h  = og * fast_tanh(c);
      unsigned short hi = f2bf(h);
      unsigned short lo = f2bf(h - bf2f(hi));
      hfh[nbuf][rt][coff + row32 * 8] = hi;
      hfl[nbuf][rt][coff + row32 * 8] = lo;
      if (!STOCH && t == NHIST - 1)
        hout[(b0 + row32) * HH + col] = h;
    }
    __syncthreads();   // B1: nbuf writes visible; old-buf reads done

    if (STOCH) {
      if (tid < 64) {   // wave 0 only: mu/ls MFMA (both rt tiles) + RNG
        facc am[2];
#pragma unroll
        for (int rr = 0; rr < 2; ++rr)
#pragma unroll
          for (int e = 0; e < 16; ++e) am[rr][e] = 0.0f;
#pragma unroll 1
        for (int kb = 0; kb < 8; ++kb) {
          const bfrag bm = *(const bfrag*)&Bmu[kb * 512 + lane * 8];
          const bfrag a0 = *(const bfrag*)&hfh[nbuf][0][kb * SKB + aoff];
          const bfrag a1 = *(const bfrag*)&hfh[nbuf][RT == 2 ? 1 : 0][kb * SKB + aoff];
          am[0] = __builtin_amdgcn_mfma_f32_32x32x16_bf16(a0, bm, am[0], 0, 0, 0);
          am[1] = __builtin_amdgcn_mfma_f32_32x32x16_bf16(a1, bm, am[1], 0, 0, 0);
        }
        if (m < 2) {
          float* dst = (m == 0) ? mu_s : ls_s;
#pragma unroll
          for (int rr = 0; rr < 2; ++rr)
#pragma unroll
            for (int reg = 0; reg < 16; ++reg)
              dst[(rr << 5) + (reg & 3) + ((reg >> 2) << 3) + (hs << 2)] = am[rr][reg];
        }
        // same-wave LDS RAW: compiler inserts lgkmcnt wait
        float mu  = mu_s[lane] + bmu;
        float lsc = fminf(fmaxf(ls_s[lane] + bls, -5.0f), 2.0f);
        float sg  = __expf(lsc);
        uint32_t k0 = keys[2 * (s * NSTEP + t)];
        uint32_t k1 = keys[2 * (s * NSTEP + t) + 1];
        float z  = normal32(k0, k1, (uint32_t)(b0 + lane));
        float xn = fmaf(sg, z + 0.5f, mu);
        logw -= fmaf(0.5f, z, 0.125f);
        if (t == TCAP) outv = xn;
        x_s[lane] = xn;
      }
      __syncthreads();  // B2: x_s ready
    }
    buf = nbuf;
  }

  if (STOCH) {
    if (tid < 64) {
      float wt = __expf(logw);
      float ow = outv * wt;
      int b = b0 + lane;
      atomicAdd(&accum[0 * NB + b], wt);
      atomicAdd(&accum[1 * NB + b], ow);
      atomicAdd(&accum[2 * NB + b], wt * wt);
      atomicAdd(&accum[3 * NB + b], ow * ow);
      atomicAdd(&accum[4 * NB + b], outv * wt * wt);
    }
  } else {
#pragma unroll
    for (int reg = 0; reg < 16; ++reg) {
      int row32 = (reg & 3) + ((reg >> 2) << 3) + (hs << 2);
      cout[(b0 + row32) * HH + col] = c_reg[reg];
    }
  }
}

// ------------------------------- final kernel ------------------------------
__global__ void final_kernel(const float* __restrict__ accum,
                             float* __restrict__ out) {
  int b = blockIdx.x * blockDim.x + threadIdx.x;
  if (b >= NB) return;
  float sw  = accum[0 * NB + b];
  float sm1 = accum[1 * NB + b];
  float sqw = accum[2 * NB + b];
  float sm2 = accum[3 * NB + b];
  float shm = accum[4 * NB + b];
  float mean = sm1 / sw;
  float sem = sm2 + sqw * mean * mean - 2.0f * shm * mean;
  sem = sqrtf(sem / (float)(NSAMP * (NSAMP - 1)));
  out[b] = mean;
  out[NB + b] = sem;
}

// ------------------------------- launcher ----------------------------------
extern "C" void kernel_launch(void* const* d_in, const int* in_sizes, int n_in,
                              void* d_out, int out_size, void* d_ws, size_t ws_size,
                              hipStream_t stream) {
  (void)in_sizes; (void)n_in; (void)out_size; (void)ws_size;
  const float* inp  = (const float*)d_in[0];
  const float* pert = (const float*)d_in[1];
  const float* W_ih = (const float*)d_in[2];
  const float* W_hh = (const float*)d_in[3];
  const float* bias = (const float*)d_in[4];
  const float* w_mu = (const float*)d_in[5];
  const float* b_mu = (const float*)d_in[6];
  const float* w_ls = (const float*)d_in[7];
  const float* b_ls = (const float*)d_in[8];

  char* ws = (char*)d_ws;
  float* ret = (float*)ws;        ws += (size_t)NRET * NB * sizeof(float);
  float* hh  = (float*)ws;        ws += (size_t)NB * HH * sizeof(float);
  float* cc  = (float*)ws;        ws += (size_t)NB * HH * sizeof(float);
  uint32_t* keys = (uint32_t*)ws; ws += (size_t)NSAMP * NSTEP * 2 * sizeof(uint32_t);
  float* accum = (float*)ws;      ws += (size_t)5 * NB * sizeof(float);
  unsigned short* Bhi = (unsigned short*)ws; ws += 65536 * sizeof(unsigned short);
  unsigned short* Blo = (unsigned short*)ws; ws += 65536 * sizeof(unsigned short);
  unsigned short* Bmu = (unsigned short*)ws; ws += 4096 * sizeof(unsigned short);

  hipMemsetAsync(accum, 0, (size_t)5 * NB * sizeof(float), stream);
  returns_kernel<<<(NRET * NB + 255) / 256, 256, 0, stream>>>(inp, pert, ret);
  keys_kernel<<<(NSAMP * NSTEP + 255) / 256, 256, 0, stream>>>(keys);
  pack_kernel<<<(65536 + 4096) / 256, 256, 0, stream>>>(W_hh, w_mu, w_ls, Bhi, Blo, Bmu);
  lstm_kernel<1, false><<<NB / 32, 256, 0, stream>>>(ret, W_ih, bias, Bhi, Blo, Bmu,
      nullptr, nullptr, hh, cc, b_mu, b_ls, keys, nullptr);
  lstm_kernel<2, true><<<NSAMP * (NB / 64), 512, 0, stream>>>(ret, W_ih, bias, Bhi, Blo, Bmu,
      hh, cc, nullptr, nullptr, b_mu, b_ls, keys, accum);
  final_kernel<<<NB / 256, 256, 0, stream>>>(accum, (float*)d_out);
}